// Round 5
// baseline (757.692 us; speedup 1.0000x reference)
//
#include <hip/hip_runtime.h>

// ---- problem constants ----
#define B_      64
#define NSEQ    482
#define DIM     512
#define HEADS_  8
#define HD      64
#define QKV3    1536
#define NPAD    512            // padded sequence length for attention tensors
#define MROWS   (B_ * NSEQ)    // 30848 = 241 * 128
#define GT      4096           // ushorts per 128x32 LDS tile buffer

typedef __bf16 v8bf __attribute__((ext_vector_type(8)));
typedef float  v4f  __attribute__((ext_vector_type(4)));
typedef unsigned int v4u __attribute__((ext_vector_type(4)));

typedef __attribute__((address_space(1))) const unsigned short gu16;
typedef __attribute__((address_space(3))) unsigned short lu16;

__device__ __forceinline__ unsigned short f2bf(float f) {
    unsigned u = __float_as_uint(f);
    u += 0x7fffu + ((u >> 16) & 1u);           // RNE
    return (unsigned short)(u >> 16);
}
__device__ __forceinline__ float bf2f(unsigned short h) {
    return __uint_as_float(((unsigned)h) << 16);
}
__device__ __forceinline__ v8bf vabs8(v8bf x) {   // |bf16| = clear sign bits
    v4u u;
    __builtin_memcpy(&u, &x, 16);
    u &= (v4u){0x7fff7fffu, 0x7fff7fffu, 0x7fff7fffu, 0x7fff7fffu};
    v8bf r;
    __builtin_memcpy(&r, &u, 16);
    return r;
}

// ---------------- conversions ----------------
__global__ void k_cvt(const float* __restrict__ s, unsigned short* __restrict__ d, int n4) {
    int i = blockIdx.x * 256 + threadIdx.x;
    if (i < n4) {
        float4 v = ((const float4*)s)[i];
        ushort4 o;
        o.x = f2bf(v.x); o.y = f2bf(v.y); o.z = f2bf(v.z); o.w = f2bf(v.w);
        ((ushort4*)d)[i] = o;
    }
}

// ---------------- fused mask bf16-convert + updated gate (single 63MB pass) ----------
__global__ __launch_bounds__(256) void k_cvtmask(const float* __restrict__ mask,
                                                 unsigned short* __restrict__ mb,
                                                 float* __restrict__ upd) {
    int row = blockIdx.x * 4 + (threadIdx.x >> 6);
    int lane = threadIdx.x & 63;
    const float4* p = (const float4*)(mask + (size_t)row * DIM);
    ushort4* d = (ushort4*)(mb + (size_t)row * DIM);
    float s = 0.f;
    #pragma unroll
    for (int j = 0; j < 2; j++) {
        float4 v = p[j * 64 + lane];
        ushort4 o;
        o.x = f2bf(v.x); o.y = f2bf(v.y); o.z = f2bf(v.z); o.w = f2bf(v.w);
        d[j * 64 + lane] = o;
        s += v.x + v.y + v.z + v.w;
    }
    #pragma unroll
    for (int off = 32; off; off >>= 1) s += __shfl_xor(s, off);
    if (lane == 0) {
        int i = row % NSEQ;
        upd[row] = (i == 0) ? 1.f : ((s > 0.f) ? 1.f : 0.f);   // mean>0 <=> sum>0
    }
}

// ---------------- fused dual bf16 GEMM, wave-split matrices ----------------
// C1[M,N] = A1[M,K] @ B[N,K]^T (+bias on f32 path), C2[M,N] = A2[M,K] @ |B|^T.
// v4: 8 waves/block (512 thr). Waves 0-3 compute C1 (A=As1, B raw), waves 4-7
// compute C2 (A=As2, B=|B| via in-reg sign-clear). Each wave owns a 64x64 tile
// of ONE matrix -> 64 acc regs (vs 128 fused-per-wave) -> 4 waves/SIMD instead
// of 2 (R4 was register-capped: 104 VGPR + 128 AGPR = 2 waves/SIMD, 20% occ,
// all pipes <30% = latency-bound). Staging still shared: A1/A2/B each loaded
// once per block (1 global_load_lds per thread per tile). 3-buffer counted
// vmcnt(3) pipeline + XCD swizzle + write-combined epilogue retained.
__global__ __launch_bounds__(512, 4) void k_gemm2(const unsigned short* __restrict__ A1,
                                                  const unsigned short* __restrict__ A2,
                                                  const unsigned short* __restrict__ Bw,
                                                  unsigned short* __restrict__ C1b,
                                                  unsigned short* __restrict__ C2b,
                                                  float* __restrict__ C1f,
                                                  float* __restrict__ C2f,
                                                  const float* __restrict__ bias,
                                                  int N, int K) {
    __shared__ __align__(16) unsigned short As1[3 * GT];
    __shared__ __align__(16) unsigned short As2[3 * GT];
    __shared__ __align__(16) unsigned short Bs[3 * GT];
    int tid = threadIdx.x;
    int lane = tid & 63, w = tid >> 6;
    int grp = w >> 2;                  // 0: C1 path, 1: C2 (|B|) path
    int wm = (w >> 1) & 1, wn = w & 1;
    int quad = lane >> 4, m16 = lane & 15;

    // bijective XCD swizzle (m204): consecutive same-XCD blocks share A panels
    int nbx = gridDim.x, nwg = nbx * gridDim.y;
    int id = blockIdx.y * nbx + blockIdx.x;
    int q = nwg >> 3, r = nwg & 7;
    int xcd = id & 7, sub = id >> 3;
    int nid = (xcd < r ? xcd * (q + 1) : r * (q + 1) + (xcd - r) * q) + sub;
    int m0 = (nid / nbx) * 128, n0 = (nid % nbx) * 128;

    // staging: thread t -> row t>>2, colblock (t&3); one 16B load per tile per thread
    int srow = tid >> 2, scol = (tid & 3) * 8;
    const unsigned short* gA1 = &A1[(size_t)(m0 + srow) * K + scol];
    const unsigned short* gA2 = &A2[(size_t)(m0 + srow) * K + scol];
    const unsigned short* gB  = &Bw[(size_t)(n0 + srow) * K + scol];
    lu16* lA1 = (lu16*)&As1[w * 512];            // HW adds lane*16B
    lu16* lA2 = (lu16*)&As2[w * 512];
    lu16* lB  = (lu16*)&Bs[w * 512];

    v4f acc[4][4];
    #pragma unroll
    for (int i = 0; i < 4; i++)
        #pragma unroll
        for (int j = 0; j < 4; j++) acc[i][j] = (v4f){0.f, 0.f, 0.f, 0.f};

    auto STAGE = [&](int bo, int s) {   // bo = buffer ushort offset {0, GT, 2GT}
        int ko = s << 5;                // K-step s -> element offset s*32
        __builtin_amdgcn_global_load_lds((gu16*)(gA1 + ko), lA1 + bo, 16, 0, 0);
        __builtin_amdgcn_global_load_lds((gu16*)(gA2 + ko), lA2 + bo, 16, 0, 0);
        __builtin_amdgcn_global_load_lds((gu16*)(gB  + ko), lB  + bo, 16, 0, 0);
    };
    const unsigned short* Ams = grp ? As2 : As1;  // wave-uniform A-tile select
    auto COMPUTE = [&](int bo) {
        v8bf a[4];
        #pragma unroll
        for (int i = 0; i < 4; i++)
            a[i] = *(const v8bf*)&Ams[bo + (wm * 64 + i * 16 + m16) * 32 + quad * 8];
        #pragma unroll
        for (int j = 0; j < 4; j++) {
            v8bf b = *(const v8bf*)&Bs[bo + (wn * 64 + j * 16 + m16) * 32 + quad * 8];
            if (grp) b = vabs8(b);     // wave-uniform branch
            #pragma unroll
            for (int i = 0; i < 4; i++)
                acc[i][j] = __builtin_amdgcn_mfma_f32_16x16x32_bf16(a[i], b, acc[i][j], 0, 0, 0);
        }
    };

    int steps = K >> 5;             // K=512 -> 16
    STAGE(0, 0);
    STAGE(GT, 1);                   // 6 loads in flight per wave
    int b0 = 0, b1 = GT, b2 = 2 * GT;
    for (int s = 0; s < steps; ++s) {
        if (s < steps - 1) asm volatile("s_waitcnt vmcnt(3)" ::: "memory");
        else               asm volatile("s_waitcnt vmcnt(0)" ::: "memory");
        __builtin_amdgcn_s_barrier();            // buf b0 staged for ALL waves
        __builtin_amdgcn_sched_barrier(0);
        if (s + 2 < steps) STAGE(b2, s + 2);     // b2 was read at step s-1; all
                                                 // waves past that via barrier
        COMPUTE(b0);
        int t = b0; b0 = b1; b1 = b2; b2 = t;
    }
    __syncthreads();                // epilogue reuses As1 as scratch

    // epilogue: D[row=quad*4+r][col=m16]  (verified C/D layout)
    if (C1f) {
        // f32: direct stores already cover full lines (64 consecutive cols/row/wave)
        float* Cf = grp ? C2f : C1f;
        #pragma unroll
        for (int j = 0; j < 4; j++) {
            int col = n0 + wn * 64 + j * 16 + m16;
            float bi = (bias && !grp) ? bias[col] : 0.f;
            #pragma unroll
            for (int i = 0; i < 4; i++) {
                int rowb = m0 + wm * 64 + i * 16 + quad * 4;
                #pragma unroll
                for (int r = 0; r < 4; r++) {
                    size_t off = (size_t)(rowb + r) * N + col;
                    Cf[off] = acc[i][j][r] + bi;
                }
            }
        }
    } else {
        // bf16: per-wave XOR-swizzled LDS repack -> dwordx4 stores (full-line HBM
        // writes). Each wave uses its own 2KB slice of As1 (8 waves x 1024 ushorts).
        unsigned short* Cb = grp ? C2b : C1b;
        unsigned short* wbuf = &As1[w * 1024];
        int rr = lane >> 2;
        int c0 = ((lane & 3) * 2) ^ ((rr >> 1) & 7);
        size_t colb = n0 + wn * 64 + (lane & 3) * 16;
        #pragma unroll
        for (int i = 0; i < 4; i++) {
            #pragma unroll
            for (int j = 0; j < 4; j++)
                #pragma unroll
                for (int r = 0; r < 4; r++) {
                    int row = quad * 4 + r;
                    int e = j * 16 + m16;
                    int es = ((((e >> 3) ^ ((row >> 1) & 7)) << 3) | (e & 7));
                    wbuf[row * 64 + es] = f2bf(acc[i][j][r]);
                }
            int4 p0 = *(const int4*)&wbuf[rr * 64 + c0 * 8];
            int4 p1 = *(const int4*)&wbuf[rr * 64 + (c0 ^ 1) * 8];
            size_t off0 = (size_t)(m0 + wm * 64 + i * 16 + rr) * N + colb;
            *(int4*)&Cb[off0] = p0;
            *(int4*)&Cb[off0 + 8] = p1;
        }
    }
}

// ---------------- per-(b,col) max over n of qkv_m -> 1/(1e-6+max) ----------------
__global__ void k_colmax(const unsigned short* __restrict__ qm, float* __restrict__ invsc) {
    int b = blockIdx.x;
    int c = blockIdx.y * 256 + threadIdx.x;
    const unsigned short* p = qm + (size_t)b * NSEQ * QKV3 + c;
    float mx = -1e30f;
    for (int i = 0; i < NSEQ; i++) mx = fmaxf(mx, bf2f(p[(size_t)i * QKV3]));
    invsc[b * QKV3 + c] = 1.f / (1e-6f + mx);
}

// ---------------- build attention operands ----------------
__global__ __launch_bounds__(256) void k_build(const unsigned short* __restrict__ qkv,
                                               const unsigned short* __restrict__ qm,
                                               const float* __restrict__ invsc,
                                               unsigned short* __restrict__ QQ,
                                               unsigned short* __restrict__ KK,
                                               unsigned short* __restrict__ VVt,
                                               unsigned short* __restrict__ VMt) {
    __shared__ unsigned short tv[64][72];
    __shared__ unsigned short tm[64][72];
    int tid = threadIdx.x;
    int dd = tid & 63, il = tid >> 6;
    int it = blockIdx.x, h = blockIdx.y, b = blockIdx.z;
    int i0 = it * 64;
    size_t bh = (size_t)(b * HEADS_ + h);
    int c = h * HD + dd;
    float invq = invsc[b * QKV3 + c] * 0.125f;   // fold softmax scale 1/sqrt(64)
    float invk = invsc[b * QKV3 + 512 + c];
    float invv = invsc[b * QKV3 + 1024 + c];
    #pragma unroll 4
    for (int p = 0; p < 16; p++) {
        int li = p * 4 + il;
        int i = i0 + li;
        unsigned short oq = 0, ok = 0, ov = 0, om = 0;
        if (i < NSEQ) {
            size_t base = ((size_t)(b * NSEQ + i)) * QKV3 + c;
            float q  = bf2f(qkv[base]),        qv = bf2f(qm[base]);
            float kk = bf2f(qkv[base + 512]),  kv = bf2f(qm[base + 512]);
            float vv = bf2f(qkv[base + 1024]), vm = bf2f(qm[base + 1024]);
            oq = f2bf(q * qv * invq);
            ok = f2bf(kk * kv * invk);
            float vmn = vm * invv;
            ov = f2bf(vv * vmn);
            om = f2bf(vmn);
        }
        QQ[(bh * NPAD + i) * HD + dd] = oq;
        KK[(bh * NPAD + i) * HD + dd] = ok;
        tv[li][dd] = ov;
        tm[li][dd] = om;
    }
    __syncthreads();
    #pragma unroll 4
    for (int p = 0; p < 16; p++) {
        int dr = p * 4 + il;
        VVt[(bh * HD + dr) * NPAD + i0 + dd] = tv[dd][dr];
        VMt[(bh * HD + dr) * NPAD + i0 + dd] = tm[dd][dr];
    }
}

// ---------------- fused flash attention, v5 ----------------
// exp-direct softmax + double-buffered K/V/M staging (1 barrier/chunk) + XCD swizzle.
__global__ __launch_bounds__(256, 3) void k_attn(const unsigned short* __restrict__ QQ,
                                                 const unsigned short* __restrict__ KK,
                                                 const unsigned short* __restrict__ VVt,
                                                 const unsigned short* __restrict__ VMt,
                                                 const float* __restrict__ upd,
                                                 float* __restrict__ OUT1,
                                                 float* __restrict__ M1) {
    __shared__ __align__(16) unsigned short Ks[2][32 * 72];     // [key][64d + 8 pad]
    __shared__ __align__(16) unsigned short Vs[2][64 * 40];     // [d][32key + 8 pad]
    __shared__ __align__(16) unsigned short Ms[2][64 * 40];
    __shared__ __align__(16) unsigned short Ps[4][32 * 40];     // per-wave P [32q][32k + 8]

    int tid = threadIdx.x;
    int w = tid >> 6, lane = tid & 63;
    int quad = lane >> 4, m16 = lane & 15;
    // XCD swizzle over 2048 blocks (divisible by 8 -> simple bijection)
    int id = (blockIdx.z * 8 + blockIdx.y) * 4 + blockIdx.x;
    int nid = (id & 7) * 256 + (id >> 3);
    int b = nid >> 5, h = (nid >> 2) & 7;
    int q0 = (nid & 3) * 128 + w * 32;
    size_t bh = (size_t)(b * HEADS_ + h);

    // Q A-frags for 2 rowsets (rows >= NSEQ are zero in QQ)
    v8bf aq[2][2];
    #pragma unroll
    for (int s = 0; s < 2; s++) {
        const unsigned short* qb = &QQ[(bh * NPAD + q0 + s * 16 + m16) * HD];
        aq[s][0] = *(const v8bf*)&qb[quad * 8];
        aq[s][1] = *(const v8bf*)&qb[32 + quad * 8];
    }

    v4f vacc[2][4], macc[2][4];
    #pragma unroll
    for (int s = 0; s < 2; s++)
        #pragma unroll
        for (int dt = 0; dt < 4; dt++) {
            vacc[s][dt] = (v4f){0.f, 0.f, 0.f, 0.f};
            macc[s][dt] = (v4f){0.f, 0.f, 0.f, 0.f};
        }
    float lrun[2][4];
    #pragma unroll
    for (int s = 0; s < 2; s++)
        #pragma unroll
        for (int r = 0; r < 4; r++) lrun[s][r] = 0.f;

    // staging pointers (chunk-invariant parts)
    const unsigned short* gK = &KK[bh * NPAD * HD + tid * 8];                       // + ic*32*HD
    const unsigned short* gV = &VVt[(bh * HD + (tid >> 2)) * NPAD + (tid & 3) * 8]; // + ic*32
    const unsigned short* gM = &VMt[(bh * HD + (tid >> 2)) * NPAD + (tid & 3) * 8];
    int oK = (tid >> 3) * 72 + (tid & 7) * 8;
    int oV = (tid >> 2) * 40 + (tid & 3) * 8;
    unsigned short* Pw = &Ps[w][0];

    int4 rk = *(const int4*)gK;          // prefetch chunk 0
    int4 rv = *(const int4*)gV;
    int4 rm = *(const int4*)gM;

    for (int ic = 0; ic < 16; ++ic) {
        int buf = ic & 1;
        *(int4*)&Ks[buf][oK] = rk;       // other waves may still read buf^1: safe
        *(int4*)&Vs[buf][oV] = rv;
        *(int4*)&Ms[buf][oV] = rm;
        if (ic < 15) {                   // prefetch chunk ic+1; latency hides under compute
            rk = *(const int4*)(gK + (ic + 1) * 32 * HD);
            rv = *(const int4*)(gV + (ic + 1) * 32);
            rm = *(const int4*)(gM + (ic + 1) * 32);
        }
        __syncthreads();                 // buf fully staged for all waves

        // QK^T: S[rowset][keytile]
        v8bf kf[2][2];
        #pragma unroll
        for (int t = 0; t < 2; t++) {
            kf[t][0] = *(const v8bf*)&Ks[buf][(t * 16 + m16) * 72 + quad * 8];
            kf[t][1] = *(const v8bf*)&Ks[buf][(t * 16 + m16) * 72 + 32 + quad * 8];
        }
        v4f S[2][2];
        #pragma unroll
        for (int s = 0; s < 2; s++)
            #pragma unroll
            for (int t = 0; t < 2; t++) {
                v4f a = (v4f){0.f, 0.f, 0.f, 0.f};
                a = __builtin_amdgcn_mfma_f32_16x16x32_bf16(aq[s][0], kf[t][0], a, 0, 0, 0);
                a = __builtin_amdgcn_mfma_f32_16x16x32_bf16(aq[s][1], kf[t][1], a, 0, 0, 0);
                S[s][t] = a;
            }

        int i0 = ic * 32;
        if (i0 + 32 > NSEQ) {            // uniform branch, last chunk only
            bool x0 = (i0 + m16) >= NSEQ;       // C-layout: col = m16
            bool x1 = (i0 + 16 + m16) >= NSEQ;
            #pragma unroll
            for (int s = 0; s < 2; s++)
                #pragma unroll
                for (int r = 0; r < 4; r++) {
                    if (x0) S[s][0][r] = -1e30f;
                    if (x1) S[s][1][r] = -1e30f;
                }
        }

        // exp-direct softmax: P = exp(S), per-lane partial row sums (reduced at end)
        #pragma unroll
        for (int s = 0; s < 2; s++)
            #pragma unroll
            for (int r = 0; r < 4; r++) {
                float e0 = __expf(S[s][0][r]);
                float e1 = __expf(S[s][1][r]);
                lrun[s][r] += e0 + e1;
                Pw[(s * 16 + quad * 4 + r) * 40 + m16] = f2bf(e0);
                Pw[(s * 16 + quad * 4 + r) * 40 + 16 + m16] = f2bf(e1);
            }

        // P: C-layout -> LDS -> A-layout (intra-wave, wave-ordered)
        v8bf ap[2];
        ap[0] = *(const v8bf*)&Pw[m16 * 40 + quad * 8];
        ap[1] = *(const v8bf*)&Pw[(16 + m16) * 40 + quad * 8];

        // PV from shared LDS V/M (B-frags identical across waves -> staged once)
        #pragma unroll
        for (int dt = 0; dt < 4; dt++) {
            v8bf bv = *(const v8bf*)&Vs[buf][(dt * 16 + m16) * 40 + quad * 8];
            v8bf bm = *(const v8bf*)&Ms[buf][(dt * 16 + m16) * 40 + quad * 8];
            #pragma unroll
            for (int s = 0; s < 2; s++) {
                vacc[s][dt] = __builtin_amdgcn_mfma_f32_16x16x32_bf16(ap[s], bv, vacc[s][dt], 0, 0, 0);
                macc[s][dt] = __builtin_amdgcn_mfma_f32_16x16x32_bf16(ap[s], bm, macc[s][dt], 0, 0, 0);
            }
        }
    }

    // final l reduction + normalized, gated outputs
    #pragma unroll
    for (int s = 0; s < 2; s++)
        #pragma unroll
        for (int r = 0; r < 4; r++) {
            float sum = lrun[s][r];
            sum += __shfl_xor(sum, 1);
            sum += __shfl_xor(sum, 2);
            sum += __shfl_xor(sum, 4);
            sum += __shfl_xor(sum, 8);
            float iv = 1.f / sum;
            int iq = q0 + s * 16 + quad * 4 + r;
            if (iq < NSEQ) {
                float u = upd[b * NSEQ + iq] * iv;
                size_t off = ((size_t)(b * NSEQ + iq)) * DIM + h * HD + m16;
                #pragma unroll
                for (int dt = 0; dt < 4; dt++) {
                    OUT1[off + dt * 16] = vacc[s][dt][r] * u;
                    M1[off + dt * 16]   = macc[s][dt][r] * u;
                }
            }
        }
}

// ---------------- overlap blending + row means (fp32), outputs bf16 GEMM inputs --------
__global__ __launch_bounds__(256) void k_blend(const float* __restrict__ O1,
                                               const float* __restrict__ Mm,
                                               const float* __restrict__ upd,
                                               unsigned short* __restrict__ O2,
                                               unsigned short* __restrict__ M2,
                                               float* __restrict__ mm) {
    int blk = blockIdx.x;
    int b = blk / NSEQ, i = blk - b * NSEQ;
    int tid = threadIdx.x;
    size_t rb = (size_t)blk * DIM;
    int ns = 0;
    size_t src[4];
    float wgt = 0.f;
    if (i >= 1) {
        wgt = 0.25f * (1.f - upd[blk]);
        if (wgt != 0.f) {
            if (i <= 256) {                       // grid row <- pooled(tail), padded pool
                int g = i - 1, gy = g >> 4, gx = g & 15;
                #pragma unroll
                for (int dy = 0; dy < 2; dy++)
                    #pragma unroll
                    for (int dx = 0; dx < 2; dx++) {
                        int sy = gy - 1 + dy, sx = gx - 1 + dx;
                        if (sy >= 0 && sy < 15 && sx >= 0 && sx < 15)
                            src[ns++] = ((size_t)(b * NSEQ + 257 + sy * 15 + sx)) * DIM;
                    }
            } else {                              // tail row <- pooled(grid), stride-1 2x2
                int t = i - 257, ty = t / 15, tx = t - ty * 15;
                #pragma unroll
                for (int dy = 0; dy < 2; dy++)
                    #pragma unroll
                    for (int dx = 0; dx < 2; dx++)
                        src[ns++] = ((size_t)(b * NSEQ + 1 + (ty + dy) * 16 + (tx + dx))) * DIM;
            }
        }
    }
    float msum = 0.f;
    for (int c = tid; c < DIM; c += 256) {
        float o = O1[rb + c], m = Mm[rb + c];
        float ao = 0.f, am = 0.f;
        for (int s = 0; s < ns; s++) { ao += O1[src[s] + c]; am += Mm[src[s] + c]; }
        o += wgt * ao;
        m += wgt * am;
        O2[rb + c] = f2bf(o);
        M2[rb + c] = f2bf(m);
        msum += m;
    }
    #pragma unroll
    for (int off = 32; off; off >>= 1) msum += __shfl_xor(msum, off);
    __shared__ float red[4];
    if ((tid & 63) == 0) red[tid >> 6] = msum;
    __syncthreads();
    if (tid == 0 && i >= 1)
        mm[b * 481 + i - 1] = (red[0] + red[1] + red[2] + red[3]) * (1.f / 512.f);
}

// ---------------- nearest-neighbor inter map ----------------
__global__ void k_inter(const float* __restrict__ mm, float* __restrict__ dst) {
    int idx = blockIdx.x * 256 + threadIdx.x;
    int b = idx >> 16, rem = idx & 65535;
    int y = rem >> 8, x = rem & 255;
    const float* mb = mm + b * 481;
    float v = mb[((y >> 4) << 4) + (x >> 4)];
    if (y >= 8 && y < 248 && x >= 8 && x < 248)
        v = 0.5f * (v + mb[256 + ((y - 8) >> 4) * 15 + ((x - 8) >> 4)]);
    dst[idx] = v;
}

// ---------------- driver ----------------
extern "C" void kernel_launch(void* const* d_in, const int* in_sizes, int n_in,
                              void* d_out, int out_size, void* d_ws, size_t ws_size,
                              hipStream_t stream) {
    const float* x    = (const float*)d_in[0];
    const float* mask = (const float*)d_in[1];
    const float* Wqkv = (const float*)d_in[2];
    const float* Wout = (const float*)d_in[3];
    const float* bout = (const float*)d_in[4];
    float* out = (float*)d_out;

    char* ws = (char*)d_ws;
    size_t o = 0;
    auto alloc = [&](size_t bytes) -> char* {
        char* r = ws + o;
        o += (bytes + 255) & ~(size_t)255;
        return r;
    };
    unsigned short* xb    = (unsigned short*)alloc((size_t)MROWS * DIM * 2);
    unsigned short* maskb = (unsigned short*)alloc((size_t)MROWS * DIM * 2);
    unsigned short* Wb    = (unsigned short*)alloc((size_t)QKV3 * DIM * 2);
    unsigned short* Wob   = (unsigned short*)alloc((size_t)DIM * DIM * 2);
    unsigned short* qkvb  = (unsigned short*)alloc((size_t)MROWS * QKV3 * 2);
    unsigned short* qkvmb = (unsigned short*)alloc((size_t)MROWS * QKV3 * 2);
    float* upd  = (float*)alloc((size_t)MROWS * 4);
    float* invs = (float*)alloc((size_t)B_ * QKV3 * 4);
    float* mm   = (float*)alloc((size_t)B_ * 481 * 4);
    unsigned short* QQ  = (unsigned short*)alloc((size_t)B_ * HEADS_ * NPAD * HD * 2);
    unsigned short* KK  = (unsigned short*)alloc((size_t)B_ * HEADS_ * NPAD * HD * 2);
    unsigned short* VVt = (unsigned short*)alloc((size_t)B_ * HEADS_ * NPAD * HD * 2);
    unsigned short* VMt = (unsigned short*)alloc((size_t)B_ * HEADS_ * NPAD * HD * 2);
    // aliases over dead buffers (qkv dead after k_build; xb/maskb dead after GEMM1)
    float* OUT1 = (float*)qkvb;
    float* M1p  = (float*)qkvmb;
    unsigned short* O2 = xb;
    unsigned short* M2 = maskb;

    // conversions + gate (mask conversion fused with gate: one pass over mask)
    k_cvt<<<(MROWS * DIM / 4) / 256, 256, 0, stream>>>(x, xb, MROWS * DIM / 4);
    k_cvtmask<<<MROWS / 4, 256, 0, stream>>>(mask, maskb, upd);
    k_cvt<<<(QKV3 * DIM / 4) / 256, 256, 0, stream>>>(Wqkv, Wb, QKV3 * DIM / 4);
    k_cvt<<<(DIM * DIM / 4) / 256, 256, 0, stream>>>(Wout, Wob, DIM * DIM / 4);

    // fused qkv projections: qkvb = x@W^T, qkvmb = mask@|W|^T (bf16 out)
    dim3 g1(QKV3 / 128, MROWS / 128);
    k_gemm2<<<g1, 512, 0, stream>>>(xb, maskb, Wb, qkvb, qkvmb,
                                    nullptr, nullptr, nullptr, QKV3, DIM);

    // normalization scales + operand build
    k_colmax<<<dim3(B_, QKV3 / 256), 256, 0, stream>>>(qkvmb, invs);
    k_build<<<dim3(8, HEADS_, B_), 256, 0, stream>>>(qkvb, qkvmb, invs, QQ, KK, VVt, VMt);

    // fused flash attention (writes gated OUT1 / M1); 128 queries/block
    k_attn<<<dim3(4, HEADS_, B_), 256, 0, stream>>>(QQ, KK, VVt, VMt, upd, OUT1, M1p);

    // overlap blend + row means, inter map
    k_blend<<<MROWS, 256, 0, stream>>>(OUT1, M1p, upd, O2, M2, mm);
    k_inter<<<(B_ * 65536) / 256, 256, 0, stream>>>(mm, out + (size_t)2 * MROWS * DIM);

    // fused output projections (f32 out into d_out): out = O2@Wo^T + b, m = M2@|Wo|^T
    dim3 g2(DIM / 128, MROWS / 128);
    k_gemm2<<<g2, 512, 0, stream>>>(O2, M2, Wob, nullptr, nullptr,
                                    out, out + (size_t)MROWS * DIM, bout, DIM, DIM);
}

// Round 6
// 727.018 us; speedup vs baseline: 1.0422x; 1.0422x over previous
//
#include <hip/hip_runtime.h>

// ---- problem constants ----
#define B_      64
#define NSEQ    482
#define DIM     512
#define HEADS_  8
#define HD      64
#define QKV3    1536
#define NPAD    512            // padded sequence length for attention tensors
#define MROWS   (B_ * NSEQ)    // 30848 = 241 * 128
#define GT      8192           // ushorts per 128x64 LDS tile buffer

typedef __bf16 v8bf __attribute__((ext_vector_type(8)));
typedef float  v4f  __attribute__((ext_vector_type(4)));
typedef unsigned int v4u __attribute__((ext_vector_type(4)));

typedef __attribute__((address_space(1))) const unsigned short gu16;
typedef __attribute__((address_space(3))) unsigned short lu16;

__device__ __forceinline__ unsigned short f2bf(float f) {
    unsigned u = __float_as_uint(f);
    u += 0x7fffu + ((u >> 16) & 1u);           // RNE
    return (unsigned short)(u >> 16);
}
__device__ __forceinline__ float bf2f(unsigned short h) {
    return __uint_as_float(((unsigned)h) << 16);
}
__device__ __forceinline__ v8bf vabs8(v8bf x) {   // |bf16| = clear sign bits
    v4u u;
    __builtin_memcpy(&u, &x, 16);
    u &= (v4u){0x7fff7fffu, 0x7fff7fffu, 0x7fff7fffu, 0x7fff7fffu};
    v8bf r;
    __builtin_memcpy(&r, &u, 16);
    return r;
}
// order-preserving float<->uint encoding (for atomicMax over signed floats)
__device__ __forceinline__ unsigned f2o(float f) {
    unsigned b = __float_as_uint(f);
    return (b & 0x80000000u) ? ~b : (b | 0x80000000u);
}

// ---------------- conversions ----------------
__global__ void k_cvt(const float* __restrict__ s, unsigned short* __restrict__ d, int n4) {
    int i = blockIdx.x * 256 + threadIdx.x;
    if (i < n4) {
        float4 v = ((const float4*)s)[i];
        ushort4 o;
        o.x = f2bf(v.x); o.y = f2bf(v.y); o.z = f2bf(v.z); o.w = f2bf(v.w);
        ((ushort4*)d)[i] = o;
    }
}

// ---------------- fused mask bf16-convert + updated gate (single 63MB pass) ----------
__global__ __launch_bounds__(256) void k_cvtmask(const float* __restrict__ mask,
                                                 unsigned short* __restrict__ mb,
                                                 float* __restrict__ upd) {
    int row = blockIdx.x * 4 + (threadIdx.x >> 6);
    int lane = threadIdx.x & 63;
    const float4* p = (const float4*)(mask + (size_t)row * DIM);
    ushort4* d = (ushort4*)(mb + (size_t)row * DIM);
    float s = 0.f;
    #pragma unroll
    for (int j = 0; j < 2; j++) {
        float4 v = p[j * 64 + lane];
        ushort4 o;
        o.x = f2bf(v.x); o.y = f2bf(v.y); o.z = f2bf(v.z); o.w = f2bf(v.w);
        d[j * 64 + lane] = o;
        s += v.x + v.y + v.z + v.w;
    }
    #pragma unroll
    for (int off = 32; off; off >>= 1) s += __shfl_xor(s, off);
    if (lane == 0) {
        int i = row % NSEQ;
        upd[row] = (i == 0) ? 1.f : ((s > 0.f) ? 1.f : 0.f);   // mean>0 <=> sum>0
    }
}

// ---------------- fused dual bf16 GEMM, BK=64 ----------------
// C1[M,N] = A1[M,K] @ B[N,K]^T (+bias on f32 path), C2[M,N] = A2[M,K] @ |B|^T.
// v5: BK=64 -> 32 MFMAs/wave per barrier period (2x R5), half the sync points
// (R3/R4/R5 all flat at ~146us across schedule variants => the per-K-step
// barrier+vmcnt was the invariant binder). 8 waves: 0-3 compute C1, 4-7 C2.
// 128B LDS rows = exact bank wrap -> REAL 16-way read conflict; fixed both-sides
// (rule #21): inverse-XOR on the GLOBAL source col (within-row perm, coalescing
// kept) + same XOR on fragment reads -> 2-way (free). Optional cm: per-(b,col)
// column max of C2 via quad-shuffle reduce + ordered-uint atomicMax (replaces
// the k_colmax 94MB pass).
__global__ __launch_bounds__(512, 2) void k_gemm2(const unsigned short* __restrict__ A1,
                                                  const unsigned short* __restrict__ A2,
                                                  const unsigned short* __restrict__ Bw,
                                                  unsigned short* __restrict__ C1b,
                                                  unsigned short* __restrict__ C2b,
                                                  float* __restrict__ C1f,
                                                  float* __restrict__ C2f,
                                                  const float* __restrict__ bias,
                                                  unsigned* __restrict__ cm,
                                                  int N, int K) {
    __shared__ __align__(16) unsigned short As1[2 * GT];
    __shared__ __align__(16) unsigned short As2[2 * GT];
    __shared__ __align__(16) unsigned short Bs[2 * GT];
    int tid = threadIdx.x;
    int lane = tid & 63, w = tid >> 6;
    int grp = w >> 2;                  // 0: C1 path, 1: C2 (|B|) path
    int ws = w & 3;
    int wm = ws >> 1, wn = ws & 1;
    int quad = lane >> 4, m16 = lane & 15;

    // bijective XCD swizzle (m204): consecutive same-XCD blocks share A panels
    int nbx = gridDim.x, nwg = nbx * gridDim.y;
    int id = blockIdx.y * nbx + blockIdx.x;
    int q = nwg >> 3, r = nwg & 7;
    int xcd = id & 7, sub = id >> 3;
    int nid = (xcd < r ? xcd * (q + 1) : r * (q + 1) + (xcd - r) * q) + sub;
    int m0 = (nid / nbx) * 128, n0 = (nid % nbx) * 128;

    // staging: 2 rounds/tile; round rr covers rows rr*64 + w*8 + (lane>>3),
    // lane colblock (lane&7), 16B each. Source col pre-swizzled cb^(row&7)
    // (row&7 == (lane>>3)&7) so linear LDS holds the swizzled layout.
    int srow = w * 8 + (lane >> 3);
    int scol = (((lane & 7) ^ (lane >> 3)) & 7) * 8;
    const unsigned short* gA1 = &A1[(size_t)(m0 + srow) * K + scol];
    const unsigned short* gA2 = &A2[(size_t)(m0 + srow) * K + scol];
    const unsigned short* gB  = &Bw[(size_t)(n0 + srow) * K + scol];
    size_t rK = (size_t)64 * K;        // round-1 row offset
    lu16* lA1 = (lu16*)&As1[w * 512];  // HW adds lane*16B; round 1 at +8*512
    lu16* lA2 = (lu16*)&As2[w * 512];
    lu16* lB  = (lu16*)&Bs[w * 512];

    v4f acc[4][4];
    #pragma unroll
    for (int i = 0; i < 4; i++)
        #pragma unroll
        for (int j = 0; j < 4; j++) acc[i][j] = (v4f){0.f, 0.f, 0.f, 0.f};

    auto STAGE = [&](int bo, int s) {   // bo = buffer ushort offset {0, GT}
        size_t ko = (size_t)(s << 6);   // K-step s -> element offset s*64
        __builtin_amdgcn_global_load_lds((gu16*)(gA1 + ko), lA1 + bo, 16, 0, 0);
        __builtin_amdgcn_global_load_lds((gu16*)(gA1 + rK + ko), lA1 + bo + 4096, 16, 0, 0);
        __builtin_amdgcn_global_load_lds((gu16*)(gA2 + ko), lA2 + bo, 16, 0, 0);
        __builtin_amdgcn_global_load_lds((gu16*)(gA2 + rK + ko), lA2 + bo + 4096, 16, 0, 0);
        __builtin_amdgcn_global_load_lds((gu16*)(gB + ko), lB + bo, 16, 0, 0);
        __builtin_amdgcn_global_load_lds((gu16*)(gB + rK + ko), lB + bo + 4096, 16, 0, 0);
    };
    const unsigned short* Ams = grp ? As2 : As1;  // wave-uniform A-tile select
    auto COMPUTE = [&](int bo) {
        v8bf a[4][2], bfr[2];
        #pragma unroll
        for (int i = 0; i < 4; i++)
            #pragma unroll
            for (int k2 = 0; k2 < 2; k2++)
                a[i][k2] = *(const v8bf*)&Ams[bo + (wm * 64 + i * 16 + m16) * 64
                                              + (((k2 * 4 + quad) ^ (m16 & 7)) * 8)];
        #pragma unroll
        for (int j = 0; j < 4; j++) {
            #pragma unroll
            for (int k2 = 0; k2 < 2; k2++) {
                v8bf b = *(const v8bf*)&Bs[bo + (wn * 64 + j * 16 + m16) * 64
                                           + (((k2 * 4 + quad) ^ (m16 & 7)) * 8)];
                bfr[k2] = grp ? vabs8(b) : b;
            }
            #pragma unroll
            for (int i = 0; i < 4; i++) {
                acc[i][j] = __builtin_amdgcn_mfma_f32_16x16x32_bf16(a[i][0], bfr[0], acc[i][j], 0, 0, 0);
                acc[i][j] = __builtin_amdgcn_mfma_f32_16x16x32_bf16(a[i][1], bfr[1], acc[i][j], 0, 0, 0);
            }
        }
    };

    int steps = K >> 6;             // K=512 -> 8
    STAGE(0, 0);
    for (int s = 0; s < steps; ++s) {
        int bo = (s & 1) * GT;
        asm volatile("s_waitcnt vmcnt(0)" ::: "memory");
        __builtin_amdgcn_s_barrier();            // buf bo staged for ALL waves;
        __builtin_amdgcn_sched_barrier(0);       // all reads of bo^GT done (see text)
        if (s + 1 < steps) STAGE(bo ^ GT, s + 1);   // in flight during COMPUTE
        __builtin_amdgcn_s_setprio(1);
        COMPUTE(bo);                             // ds_reads consumed by MFMAs before
        __builtin_amdgcn_s_setprio(0);           // this wave reaches the next barrier
    }
    __syncthreads();                // epilogue reuses As1 as scratch

    // optional: per-(b,col) max of C2 (f32, pre-rounding) -> cm via atomicMax
    if (cm && grp) {
        int bb0 = (m0 + wm * 64) / NSEQ;
        int bound = (bb0 + 1) * NSEQ;
        int rbase = m0 + wm * 64;
        bool spill = (bound < rbase + 64);
        #pragma unroll
        for (int j = 0; j < 4; j++) {
            float mx0 = -1e30f, mx1 = -1e30f;
            #pragma unroll
            for (int i = 0; i < 4; i++)
                #pragma unroll
                for (int rr = 0; rr < 4; rr++) {
                    int row = rbase + i * 16 + quad * 4 + rr;
                    float v = acc[i][j][rr];
                    if (row < bound) mx0 = fmaxf(mx0, v);
                    else             mx1 = fmaxf(mx1, v);
                }
            mx0 = fmaxf(mx0, __shfl_xor(mx0, 16));
            mx0 = fmaxf(mx0, __shfl_xor(mx0, 32));
            mx1 = fmaxf(mx1, __shfl_xor(mx1, 16));
            mx1 = fmaxf(mx1, __shfl_xor(mx1, 32));
            if (quad == 0) {
                int col = n0 + wn * 64 + j * 16 + m16;
                atomicMax(&cm[bb0 * N + col], f2o(mx0));
                if (spill) atomicMax(&cm[(bb0 + 1) * N + col], f2o(mx1));
            }
        }
    }

    // epilogue: D[row=quad*4+r][col=m16]  (verified C/D layout)
    if (C1f) {
        // f32: direct stores already cover full lines (64 consecutive cols/row/wave)
        float* Cf = grp ? C2f : C1f;
        #pragma unroll
        for (int j = 0; j < 4; j++) {
            int col = n0 + wn * 64 + j * 16 + m16;
            float bi = (bias && !grp) ? bias[col] : 0.f;
            #pragma unroll
            for (int i = 0; i < 4; i++) {
                int rowb = m0 + wm * 64 + i * 16 + quad * 4;
                #pragma unroll
                for (int r2 = 0; r2 < 4; r2++) {
                    size_t off = (size_t)(rowb + r2) * N + col;
                    Cf[off] = acc[i][j][r2] + bi;
                }
            }
        }
    } else {
        // bf16: per-wave XOR-swizzled LDS repack -> dwordx4 stores (full-line HBM
        // writes). Each wave uses its own 2KB slice of As1 (8 waves x 1024 ushorts).
        unsigned short* Cb = grp ? C2b : C1b;
        unsigned short* wbuf = &As1[w * 1024];
        int rr = lane >> 2;
        int c0 = ((lane & 3) * 2) ^ ((rr >> 1) & 7);
        size_t colb = n0 + wn * 64 + (lane & 3) * 16;
        #pragma unroll
        for (int i = 0; i < 4; i++) {
            #pragma unroll
            for (int j = 0; j < 4; j++)
                #pragma unroll
                for (int r2 = 0; r2 < 4; r2++) {
                    int row = quad * 4 + r2;
                    int e = j * 16 + m16;
                    int es = ((((e >> 3) ^ ((row >> 1) & 7)) << 3) | (e & 7));
                    wbuf[row * 64 + es] = f2bf(acc[i][j][r2]);
                }
            int4 p0 = *(const int4*)&wbuf[rr * 64 + c0 * 8];
            int4 p1 = *(const int4*)&wbuf[rr * 64 + (c0 ^ 1) * 8];
            size_t off0 = (size_t)(m0 + wm * 64 + i * 16 + rr) * N + colb;
            *(int4*)&Cb[off0] = p0;
            *(int4*)&Cb[off0 + 8] = p1;
        }
    }
}

// ---------------- decode ordered-uint max -> 1/(1e-6+max), in place ----------------
__global__ void k_invs(float* __restrict__ p, int n) {
    int i = blockIdx.x * 256 + threadIdx.x;
    if (i < n) {
        unsigned u = ((const unsigned*)p)[i];
        unsigned b = (u & 0x80000000u) ? (u & 0x7fffffffu) : ~u;
        p[i] = 1.f / (1e-6f + __uint_as_float(b));
    }
}

// ---------------- build attention operands ----------------
__global__ __launch_bounds__(256) void k_build(const unsigned short* __restrict__ qkv,
                                               const unsigned short* __restrict__ qm,
                                               const float* __restrict__ invsc,
                                               unsigned short* __restrict__ QQ,
                                               unsigned short* __restrict__ KK,
                                               unsigned short* __restrict__ VVt,
                                               unsigned short* __restrict__ VMt) {
    __shared__ unsigned short tv[64][72];
    __shared__ unsigned short tm[64][72];
    int tid = threadIdx.x;
    int dd = tid & 63, il = tid >> 6;
    int it = blockIdx.x, h = blockIdx.y, b = blockIdx.z;
    int i0 = it * 64;
    size_t bh = (size_t)(b * HEADS_ + h);
    int c = h * HD + dd;
    float invq = invsc[b * QKV3 + c] * 0.125f;   // fold softmax scale 1/sqrt(64)
    float invk = invsc[b * QKV3 + 512 + c];
    float invv = invsc[b * QKV3 + 1024 + c];
    #pragma unroll 4
    for (int p = 0; p < 16; p++) {
        int li = p * 4 + il;
        int i = i0 + li;
        unsigned short oq = 0, ok = 0, ov = 0, om = 0;
        if (i < NSEQ) {
            size_t base = ((size_t)(b * NSEQ + i)) * QKV3 + c;
            float q  = bf2f(qkv[base]),        qv = bf2f(qm[base]);
            float kk = bf2f(qkv[base + 512]),  kv = bf2f(qm[base + 512]);
            float vv = bf2f(qkv[base + 1024]), vm = bf2f(qm[base + 1024]);
            oq = f2bf(q * qv * invq);
            ok = f2bf(kk * kv * invk);
            float vmn = vm * invv;
            ov = f2bf(vv * vmn);
            om = f2bf(vmn);
        }
        QQ[(bh * NPAD + i) * HD + dd] = oq;
        KK[(bh * NPAD + i) * HD + dd] = ok;
        tv[li][dd] = ov;
        tm[li][dd] = om;
    }
    __syncthreads();
    #pragma unroll 4
    for (int p = 0; p < 16; p++) {
        int dr = p * 4 + il;
        VVt[(bh * HD + dr) * NPAD + i0 + dd] = tv[dd][dr];
        VMt[(bh * HD + dr) * NPAD + i0 + dd] = tm[dd][dr];
    }
}

// ---------------- fused flash attention, v6 ----------------
// exp-direct softmax + double-buffered K/V/M staging (1 barrier/chunk) + XCD
// swizzle + setprio around MFMA clusters (T5, +4-7% proven on attention).
__global__ __launch_bounds__(256, 3) void k_attn(const unsigned short* __restrict__ QQ,
                                                 const unsigned short* __restrict__ KK,
                                                 const unsigned short* __restrict__ VVt,
                                                 const unsigned short* __restrict__ VMt,
                                                 const float* __restrict__ upd,
                                                 float* __restrict__ OUT1,
                                                 float* __restrict__ M1) {
    __shared__ __align__(16) unsigned short Ks[2][32 * 72];     // [key][64d + 8 pad]
    __shared__ __align__(16) unsigned short Vs[2][64 * 40];     // [d][32key + 8 pad]
    __shared__ __align__(16) unsigned short Ms[2][64 * 40];
    __shared__ __align__(16) unsigned short Ps[4][32 * 40];     // per-wave P [32q][32k + 8]

    int tid = threadIdx.x;
    int w = tid >> 6, lane = tid & 63;
    int quad = lane >> 4, m16 = lane & 15;
    // XCD swizzle over 2048 blocks (divisible by 8 -> simple bijection)
    int id = (blockIdx.z * 8 + blockIdx.y) * 4 + blockIdx.x;
    int nid = (id & 7) * 256 + (id >> 3);
    int b = nid >> 5, h = (nid >> 2) & 7;
    int q0 = (nid & 3) * 128 + w * 32;
    size_t bh = (size_t)(b * HEADS_ + h);

    // Q A-frags for 2 rowsets (rows >= NSEQ are zero in QQ)
    v8bf aq[2][2];
    #pragma unroll
    for (int s = 0; s < 2; s++) {
        const unsigned short* qb = &QQ[(bh * NPAD + q0 + s * 16 + m16) * HD];
        aq[s][0] = *(const v8bf*)&qb[quad * 8];
        aq[s][1] = *(const v8bf*)&qb[32 + quad * 8];
    }

    v4f vacc[2][4], macc[2][4];
    #pragma unroll
    for (int s = 0; s < 2; s++)
        #pragma unroll
        for (int dt = 0; dt < 4; dt++) {
            vacc[s][dt] = (v4f){0.f, 0.f, 0.f, 0.f};
            macc[s][dt] = (v4f){0.f, 0.f, 0.f, 0.f};
        }
    float lrun[2][4];
    #pragma unroll
    for (int s = 0; s < 2; s++)
        #pragma unroll
        for (int r = 0; r < 4; r++) lrun[s][r] = 0.f;

    // staging pointers (chunk-invariant parts)
    const unsigned short* gK = &KK[bh * NPAD * HD + tid * 8];                       // + ic*32*HD
    const unsigned short* gV = &VVt[(bh * HD + (tid >> 2)) * NPAD + (tid & 3) * 8]; // + ic*32
    const unsigned short* gM = &VMt[(bh * HD + (tid >> 2)) * NPAD + (tid & 3) * 8];
    int oK = (tid >> 3) * 72 + (tid & 7) * 8;
    int oV = (tid >> 2) * 40 + (tid & 3) * 8;
    unsigned short* Pw = &Ps[w][0];

    int4 rk = *(const int4*)gK;          // prefetch chunk 0
    int4 rv = *(const int4*)gV;
    int4 rm = *(const int4*)gM;

    for (int ic = 0; ic < 16; ++ic) {
        int buf = ic & 1;
        *(int4*)&Ks[buf][oK] = rk;       // other waves may still read buf^1: safe
        *(int4*)&Vs[buf][oV] = rv;
        *(int4*)&Ms[buf][oV] = rm;
        if (ic < 15) {                   // prefetch chunk ic+1; latency hides under compute
            rk = *(const int4*)(gK + (ic + 1) * 32 * HD);
            rv = *(const int4*)(gV + (ic + 1) * 32);
            rm = *(const int4*)(gM + (ic + 1) * 32);
        }
        __syncthreads();                 // buf fully staged for all waves

        // QK^T: S[rowset][keytile]
        v8bf kf[2][2];
        #pragma unroll
        for (int t = 0; t < 2; t++) {
            kf[t][0] = *(const v8bf*)&Ks[buf][(t * 16 + m16) * 72 + quad * 8];
            kf[t][1] = *(const v8bf*)&Ks[buf][(t * 16 + m16) * 72 + 32 + quad * 8];
        }
        v4f S[2][2];
        __builtin_amdgcn_s_setprio(1);
        #pragma unroll
        for (int s = 0; s < 2; s++)
            #pragma unroll
            for (int t = 0; t < 2; t++) {
                v4f a = (v4f){0.f, 0.f, 0.f, 0.f};
                a = __builtin_amdgcn_mfma_f32_16x16x32_bf16(aq[s][0], kf[t][0], a, 0, 0, 0);
                a = __builtin_amdgcn_mfma_f32_16x16x32_bf16(aq[s][1], kf[t][1], a, 0, 0, 0);
                S[s][t] = a;
            }
        __builtin_amdgcn_s_setprio(0);

        int i0 = ic * 32;
        if (i0 + 32 > NSEQ) {            // uniform branch, last chunk only
            bool x0 = (i0 + m16) >= NSEQ;       // C-layout: col = m16
            bool x1 = (i0 + 16 + m16) >= NSEQ;
            #pragma unroll
            for (int s = 0; s < 2; s++)
                #pragma unroll
                for (int r = 0; r < 4; r++) {
                    if (x0) S[s][0][r] = -1e30f;
                    if (x1) S[s][1][r] = -1e30f;
                }
        }

        // exp-direct softmax: P = exp(S), per-lane partial row sums (reduced at end)
        #pragma unroll
        for (int s = 0; s < 2; s++)
            #pragma unroll
            for (int r = 0; r < 4; r++) {
                float e0 = __expf(S[s][0][r]);
                float e1 = __expf(S[s][1][r]);
                lrun[s][r] += e0 + e1;
                Pw[(s * 16 + quad * 4 + r) * 40 + m16] = f2bf(e0);
                Pw[(s * 16 + quad * 4 + r) * 40 + 16 + m16] = f2bf(e1);
            }

        // P: C-layout -> LDS -> A-layout (intra-wave, wave-ordered)
        v8bf ap[2];
        ap[0] = *(const v8bf*)&Pw[m16 * 40 + quad * 8];
        ap[1] = *(const v8bf*)&Pw[(16 + m16) * 40 + quad * 8];

        // PV from shared LDS V/M (B-frags identical across waves -> staged once)
        __builtin_amdgcn_s_setprio(1);
        #pragma unroll
        for (int dt = 0; dt < 4; dt++) {
            v8bf bv = *(const v8bf*)&Vs[buf][(dt * 16 + m16) * 40 + quad * 8];
            v8bf bm = *(const v8bf*)&Ms[buf][(dt * 16 + m16) * 40 + quad * 8];
            #pragma unroll
            for (int s = 0; s < 2; s++) {
                vacc[s][dt] = __builtin_amdgcn_mfma_f32_16x16x32_bf16(ap[s], bv, vacc[s][dt], 0, 0, 0);
                macc[s][dt] = __builtin_amdgcn_mfma_f32_16x16x32_bf16(ap[s], bm, macc[s][dt], 0, 0, 0);
            }
        }
        __builtin_amdgcn_s_setprio(0);
    }

    // final l reduction + normalized, gated outputs
    #pragma unroll
    for (int s = 0; s < 2; s++)
        #pragma unroll
        for (int r = 0; r < 4; r++) {
            float sum = lrun[s][r];
            sum += __shfl_xor(sum, 1);
            sum += __shfl_xor(sum, 2);
            sum += __shfl_xor(sum, 4);
            sum += __shfl_xor(sum, 8);
            float iv = 1.f / sum;
            int iq = q0 + s * 16 + quad * 4 + r;
            if (iq < NSEQ) {
                float u = upd[b * NSEQ + iq] * iv;
                size_t off = ((size_t)(b * NSEQ + iq)) * DIM + h * HD + m16;
                #pragma unroll
                for (int dt = 0; dt < 4; dt++) {
                    OUT1[off + dt * 16] = vacc[s][dt][r] * u;
                    M1[off + dt * 16]   = macc[s][dt][r] * u;
                }
            }
        }
}

// ---------------- overlap blending + row means (fp32), outputs bf16 GEMM inputs --------
__global__ __launch_bounds__(256) void k_blend(const float* __restrict__ O1,
                                               const float* __restrict__ Mm,
                                               const float* __restrict__ upd,
                                               unsigned short* __restrict__ O2,
                                               unsigned short* __restrict__ M2,
                                               float* __restrict__ mm) {
    int blk = blockIdx.x;
    int b = blk / NSEQ, i = blk - b * NSEQ;
    int tid = threadIdx.x;
    size_t rb = (size_t)blk * DIM;
    int ns = 0;
    size_t src[4];
    float wgt = 0.f;
    if (i >= 1) {
        wgt = 0.25f * (1.f - upd[blk]);
        if (wgt != 0.f) {
            if (i <= 256) {                       // grid row <- pooled(tail), padded pool
                int g = i - 1, gy = g >> 4, gx = g & 15;
                #pragma unroll
                for (int dy = 0; dy < 2; dy++)
                    #pragma unroll
                    for (int dx = 0; dx < 2; dx++) {
                        int sy = gy - 1 + dy, sx = gx - 1 + dx;
                        if (sy >= 0 && sy < 15 && sx >= 0 && sx < 15)
                            src[ns++] = ((size_t)(b * NSEQ + 257 + sy * 15 + sx)) * DIM;
                    }
            } else {                              // tail row <- pooled(grid), stride-1 2x2
                int t = i - 257, ty = t / 15, tx = t - ty * 15;
                #pragma unroll
                for (int dy = 0; dy < 2; dy++)
                    #pragma unroll
                    for (int dx = 0; dx < 2; dx++)
                        src[ns++] = ((size_t)(b * NSEQ + 1 + (ty + dy) * 16 + (tx + dx))) * DIM;
            }
        }
    }
    float msum = 0.f;
    for (int c = tid; c < DIM; c += 256) {
        float o = O1[rb + c], m = Mm[rb + c];
        float ao = 0.f, am = 0.f;
        for (int s = 0; s < ns; s++) { ao += O1[src[s] + c]; am += Mm[src[s] + c]; }
        o += wgt * ao;
        m += wgt * am;
        O2[rb + c] = f2bf(o);
        M2[rb + c] = f2bf(m);
        msum += m;
    }
    #pragma unroll
    for (int off = 32; off; off >>= 1) msum += __shfl_xor(msum, off);
    __shared__ float red[4];
    if ((tid & 63) == 0) red[tid >> 6] = msum;
    __syncthreads();
    if (tid == 0 && i >= 1)
        mm[b * 481 + i - 1] = (red[0] + red[1] + red[2] + red[3]) * (1.f / 512.f);
}

// ---------------- nearest-neighbor inter map ----------------
__global__ void k_inter(const float* __restrict__ mm, float* __restrict__ dst) {
    int idx = blockIdx.x * 256 + threadIdx.x;
    int b = idx >> 16, rem = idx & 65535;
    int y = rem >> 8, x = rem & 255;
    const float* mb = mm + b * 481;
    float v = mb[((y >> 4) << 4) + (x >> 4)];
    if (y >= 8 && y < 248 && x >= 8 && x < 248)
        v = 0.5f * (v + mb[256 + ((y - 8) >> 4) * 15 + ((x - 8) >> 4)]);
    dst[idx] = v;
}

// ---------------- driver ----------------
extern "C" void kernel_launch(void* const* d_in, const int* in_sizes, int n_in,
                              void* d_out, int out_size, void* d_ws, size_t ws_size,
                              hipStream_t stream) {
    const float* x    = (const float*)d_in[0];
    const float* mask = (const float*)d_in[1];
    const float* Wqkv = (const float*)d_in[2];
    const float* Wout = (const float*)d_in[3];
    const float* bout = (const float*)d_in[4];
    float* out = (float*)d_out;

    char* ws = (char*)d_ws;
    size_t o = 0;
    auto alloc = [&](size_t bytes) -> char* {
        char* r = ws + o;
        o += (bytes + 255) & ~(size_t)255;
        return r;
    };
    unsigned short* xb    = (unsigned short*)alloc((size_t)MROWS * DIM * 2);
    unsigned short* maskb = (unsigned short*)alloc((size_t)MROWS * DIM * 2);
    unsigned short* Wb    = (unsigned short*)alloc((size_t)QKV3 * DIM * 2);
    unsigned short* Wob   = (unsigned short*)alloc((size_t)DIM * DIM * 2);
    unsigned short* qkvb  = (unsigned short*)alloc((size_t)MROWS * QKV3 * 2);
    unsigned short* qkvmb = (unsigned short*)alloc((size_t)MROWS * QKV3 * 2);
    float* upd  = (float*)alloc((size_t)MROWS * 4);
    float* invs = (float*)alloc((size_t)B_ * QKV3 * 4);
    float* mm   = (float*)alloc((size_t)B_ * 481 * 4);
    unsigned short* QQ  = (unsigned short*)alloc((size_t)B_ * HEADS_ * NPAD * HD * 2);
    unsigned short* KK  = (unsigned short*)alloc((size_t)B_ * HEADS_ * NPAD * HD * 2);
    unsigned short* VVt = (unsigned short*)alloc((size_t)B_ * HEADS_ * NPAD * HD * 2);
    unsigned short* VMt = (unsigned short*)alloc((size_t)B_ * HEADS_ * NPAD * HD * 2);
    // aliases over dead buffers (qkv dead after k_build; xb/maskb dead after GEMM1)
    float* OUT1 = (float*)qkvb;
    float* M1p  = (float*)qkvmb;
    unsigned short* O2 = xb;
    unsigned short* M2 = maskb;

    // conversions + gate (mask conversion fused with gate: one pass over mask)
    k_cvt<<<(MROWS * DIM / 4) / 256, 256, 0, stream>>>(x, xb, MROWS * DIM / 4);
    k_cvtmask<<<MROWS / 4, 256, 0, stream>>>(mask, maskb, upd);
    k_cvt<<<(QKV3 * DIM / 4) / 256, 256, 0, stream>>>(Wqkv, Wb, QKV3 * DIM / 4);
    k_cvt<<<(DIM * DIM / 4) / 256, 256, 0, stream>>>(Wout, Wob, DIM * DIM / 4);
    hipMemsetAsync(invs, 0, (size_t)B_ * QKV3 * 4, stream);  // ordered-uint max init

    // fused qkv projections: qkvb = x@W^T, qkvmb = mask@|W|^T (bf16 out),
    // column-max of qkvmb folded into the epilogue (replaces k_colmax)
    dim3 g1(QKV3 / 128, MROWS / 128);
    k_gemm2<<<g1, 512, 0, stream>>>(xb, maskb, Wb, qkvb, qkvmb,
                                    nullptr, nullptr, nullptr, (unsigned*)invs,
                                    QKV3, DIM);

    // normalization scales + operand build
    k_invs<<<(B_ * QKV3) / 256, 256, 0, stream>>>(invs, B_ * QKV3);
    k_build<<<dim3(8, HEADS_, B_), 256, 0, stream>>>(qkvb, qkvmb, invs, QQ, KK, VVt, VMt);

    // fused flash attention (writes gated OUT1 / M1); 128 queries/block
    k_attn<<<dim3(4, HEADS_, B_), 256, 0, stream>>>(QQ, KK, VVt, VMt, upd, OUT1, M1p);

    // overlap blend + row means, inter map
    k_blend<<<MROWS, 256, 0, stream>>>(OUT1, M1p, upd, O2, M2, mm);
    k_inter<<<(B_ * 65536) / 256, 256, 0, stream>>>(mm, out + (size_t)2 * MROWS * DIM);

    // fused output projections (f32 out into d_out): out = O2@Wo^T + b, m = M2@|Wo|^T
    dim3 g2(DIM / 128, MROWS / 128);
    k_gemm2<<<g2, 512, 0, stream>>>(O2, M2, Wob, nullptr, nullptr,
                                    out, out + (size_t)MROWS * DIM, bout, nullptr,
                                    DIM, DIM);
}